// Round 11
// baseline (117287.378 us; speedup 1.0000x reference)
//
#include <hip/hip_runtime.h>
#include <stdint.h>

// 2-layer bidirectional LSTM, T=512 B=64 D=512 H=512.
// R10 phase kernels UNCHANGED (passing, 4.35ms/phase). This round adds three
// DIAGNOSTIC PROBE kernels (run after the phases, write only to ws scratch)
// sized >4.4ms each so they appear in rocprof's top-5-by-duration table:
//   probe_exch64: R10 exchange path only (sync+LLC traffic), 3072 iters
//   probe_exch8:  same protocol, fan-in 8, 1/8 bulk bytes, 8192 iters
//   probe_comp:   R10 per-step compute only (no sync/coherence), 12288 iters
// Decomposes the invariant ~8.5us/step floor: exchange vs compute vs interaction.

#define TT 512
#define BATCH 64
#define HH 512
#define NWG 64
#define NCOLS 32

typedef __attribute__((ext_vector_type(8))) short vshort8;
typedef __attribute__((ext_vector_type(4))) float vfloat4;

__device__ __forceinline__ vfloat4 mfma16(vshort8 a, vshort8 b, vfloat4 c) {
    return __builtin_amdgcn_mfma_f32_16x16x32_bf16(a, b, c, 0, 0, 0);
}

__device__ __forceinline__ float sigmoidf_(float x) {
    return 1.f / (1.f + __expf(-x));
}
__device__ __forceinline__ float tanhf_(float x) {
    float e = __expf(2.f * x);
    return 1.f - 2.f / (e + 1.f);
}
__device__ __forceinline__ unsigned short f2bf(float f) {
    uint32_t u = __float_as_uint(f);
    uint32_t r = (u + 0x7fffu + ((u >> 16) & 1u)) >> 16;
    return (unsigned short)r;
}

__global__ void cvt_f32_bf16(const float* __restrict__ src,
                             unsigned short* __restrict__ dst, int n) {
    int i = (blockIdx.x * blockDim.x + threadIdx.x) * 4;
    if (i + 3 < n) {
        float4 v = *(const float4*)(src + i);
        uint2 p;
        p.x = (uint32_t)f2bf(v.x) | ((uint32_t)f2bf(v.y) << 16);
        p.y = (uint32_t)f2bf(v.z) | ((uint32_t)f2bf(v.w) << 16);
        *(uint2*)(dst + i) = p;
    }
}

// ======================= R10 phase kernel (unchanged) =======================
template <int DIN, bool WRITE_BF16>
__launch_bounds__(256, 1)
__global__ void lstm_phase(const unsigned short* __restrict__ A,
                           const unsigned short* __restrict__ Wi,
                           const float* __restrict__ Whf,
                           const float* __restrict__ bias,
                           unsigned short* __restrict__ hbuf,
                           uint32_t* __restrict__ cnt,
                           unsigned short* __restrict__ obf,
                           float* __restrict__ of32,
                           float* __restrict__ hn,
                           float* __restrict__ cn)
{
    __shared__ unsigned short Wlds[NCOLS * 1024];
    __shared__ unsigned short Wpad[16 * 1024];

    const int tid = threadIdx.x;
    ((volatile unsigned short*)Wpad)[tid] = 0;

    const int dir = blockIdx.x >> 6;
    const int wg = blockIdx.x & 63;
    const int j0 = wg * 8;
    const int lane = tid & 63;
    const int wave = tid >> 6;

    for (int chunk = tid; chunk < NCOLS * DIN / 8; chunk += 256) {
        int n = chunk / (DIN / 8);
        int k8 = (chunk % (DIN / 8)) * 8;
        int grow = (n >> 3) * HH + j0 + (n & 7);
        vshort8 v = *(const vshort8*)(Wi + ((size_t)dir * 4 * HH + grow) * DIN + k8);
        int byte = n * DIN * 2 + ((k8 * 2) ^ ((n & 7) << 4));
        *(vshort8*)((char*)Wlds + byte) = v;
    }
    __syncthreads();

    const int arow = wave * 16 + (lane & 15);
    const int kOff = (lane >> 4) * 8;
    const int klane = (lane >> 4) * 16;
    const int n0 = lane & 15;
    const int swz = (n0 & 7) << 4;
    const int nb0 = n0 * DIN * 2;
    const int nb1 = (16 + n0) * DIN * 2;
    const int grow0 = (n0 >> 3) * HH + j0 + (n0 & 7);
    const int grow1 = ((n0 >> 3) + 2) * HH + j0 + (n0 & 7);
    const float bias0 = bias[dir * 4 * HH + grow0];
    const float bias1 = bias[dir * 4 * HH + grow1];
    const bool lo = (lane & 8) == 0;
    const int jcol = j0 + (lane & 7);
    const int hrowb = wave * 16 + ((lane >> 4) << 2);
    uint32_t* const cline = cnt + (dir * 4 + wave) * 32;

    const float* whf0 = Whf + ((size_t)dir * 4 * HH + grow0) * HH + kOff;
    const float* whf1 = Whf + ((size_t)dir * 4 * HH + grow1) * HH + kOff;
    vshort8 wh0r[16], wh1r[16];
#pragma unroll
    for (int kk = 0; kk < 16; ++kk) {
        float4 a0 = *(const float4*)(whf0 + kk * 32);
        float4 a1 = *(const float4*)(whf0 + kk * 32 + 4);
        float4 b0 = *(const float4*)(whf1 + kk * 32);
        float4 b1 = *(const float4*)(whf1 + kk * 32 + 4);
        vshort8 a, b;
        a[0] = (short)f2bf(a0.x); a[1] = (short)f2bf(a0.y);
        a[2] = (short)f2bf(a0.z); a[3] = (short)f2bf(a0.w);
        a[4] = (short)f2bf(a1.x); a[5] = (short)f2bf(a1.y);
        a[6] = (short)f2bf(a1.z); a[7] = (short)f2bf(a1.w);
        b[0] = (short)f2bf(b0.x); b[1] = (short)f2bf(b0.y);
        b[2] = (short)f2bf(b0.z); b[3] = (short)f2bf(b0.w);
        b[4] = (short)f2bf(b1.x); b[5] = (short)f2bf(b1.y);
        b[6] = (short)f2bf(b1.z); b[7] = (short)f2bf(b1.w);
        wh0r[kk] = a;
        wh1r[kk] = b;
        asm volatile("" : "+v"(wh0r[kk]), "+v"(wh1r[kk]));
    }

    float cstate[4] = {0.f, 0.f, 0.f, 0.f};

    for (int s = 0; s < TT; ++s) {
        const int t = dir ? (TT - 1 - s) : s;

        vfloat4 acc0, acc1;
        acc0[0] = acc0[1] = acc0[2] = acc0[3] = bias0;
        acc1[0] = acc1[1] = acc1[2] = acc1[3] = bias1;

        const unsigned short* ap = A + ((size_t)t * BATCH + arow) * DIN + kOff;
#pragma unroll 8
        for (int kk = 0; kk < DIN / 32; ++kk) {
            vshort8 a = *(const vshort8*)(ap + kk * 32);
            int kb = kk * 64 + klane;
            vshort8 b0 = *(const vshort8*)((const char*)Wlds + nb0 + (kb ^ swz));
            vshort8 b1 = *(const vshort8*)((const char*)Wlds + nb1 + (kb ^ swz));
            acc0 = mfma16(a, b0, acc0);
            acc1 = mfma16(a, b1, acc1);
        }

        if (s > 0) {
            const uint32_t target = 64u * (uint32_t)s;
            for (;;) {
                uint32_t v;
                asm volatile(
                    "global_load_dword %0, %1, off sc0 sc1\n\t"
                    "s_waitcnt vmcnt(0)"
                    : "=v"(v) : "v"(cline) : "memory");
                if (__builtin_amdgcn_readfirstlane(v) >= target) break;
                __builtin_amdgcn_s_sleep(1);
            }
            __builtin_amdgcn_sched_barrier(0);

            const unsigned short* hp =
                hbuf + (((dir << 1) | ((s - 1) & 1)) * BATCH + arow) * HH + kOff;
            vshort8 hd[16];
#pragma unroll
            for (int kk = 0; kk < 16; ++kk)
                asm volatile("global_load_dwordx4 %0, %1, off sc0 sc1"
                             : "=v"(hd[kk]) : "v"(hp + kk * 32));
            asm volatile("s_waitcnt vmcnt(0)" ::: "memory");
            __builtin_amdgcn_sched_barrier(0);
#pragma unroll
            for (int kk = 0; kk < 16; ++kk) {
                acc0 = mfma16(hd[kk], wh0r[kk], acc0);
                acc1 = mfma16(hd[kk], wh1r[kk], acc1);
            }
        }

        float hval[4];
#pragma unroll
        for (int r = 0; r < 4; ++r) {
            float own0 = acc0[r], own1 = acc1[r];
            float oth0 = __shfl_xor(own0, 8, 64);
            float oth1 = __shfl_xor(own1, 8, 64);
            float iv = lo ? own0 : oth0;
            float fv = lo ? oth0 : own0;
            float gv = lo ? own1 : oth1;
            float ov = lo ? oth1 : own1;
            float cnew = sigmoidf_(fv) * cstate[r] + sigmoidf_(iv) * tanhf_(gv);
            cstate[r] = cnew;
            hval[r] = sigmoidf_(ov) * tanhf_(cnew);
        }

        unsigned short* hw = hbuf + (size_t)(((dir << 1) | (s & 1)) * BATCH) * HH;
        const int rA = lo ? 0 : 2;
        unsigned short hb[2];
        hb[0] = f2bf(hval[rA]);
        hb[1] = f2bf(hval[rA + 1]);
#pragma unroll
        for (int q = 0; q < 2; ++q) {
            int row = hrowb + rA + q;
            unsigned short* wp = hw + row * HH + jcol;
            uint32_t v32 = hb[q];
            asm volatile("global_store_short %0, %1, off sc0 sc1"
                         :: "v"(wp), "v"(v32) : "memory");
        }
        asm volatile("s_waitcnt vmcnt(0)" ::: "memory");
        __builtin_amdgcn_sched_barrier(0);
        if (lane == 0) atomicAdd((unsigned int*)cline, 1u);

#pragma unroll
        for (int q = 0; q < 2; ++q) {
            int row = hrowb + rA + q;
            if constexpr (WRITE_BF16)
                obf[((size_t)t * BATCH + row) * (2 * HH) + dir * HH + jcol] = hb[q];
            else
                of32[((size_t)t * BATCH + row) * (2 * HH) + dir * HH + jcol] =
                    hval[q == 0 ? rA : rA + 1];
        }
        if (s == TT - 1) {
#pragma unroll
            for (int q = 0; q < 2; ++q) {
                int r = rA + q, row = hrowb + r;
                hn[(dir * BATCH + row) * HH + jcol] = hval[r];
                cn[(dir * BATCH + row) * HH + jcol] = cstate[r];
            }
        }
    }
}

// ======================= probe: exchange only, fan-in 64 ====================
__launch_bounds__(256, 1)
__global__ void probe_exch64(unsigned short* __restrict__ hbuf,
                             uint32_t* __restrict__ cnt, int iters) {
    __shared__ unsigned short pad[48 * 1024];  // 96KB -> 1 WG/CU (parity)
    ((volatile unsigned short*)pad)[threadIdx.x] = 0;
    const int tid = threadIdx.x;
    const int dir = blockIdx.x >> 6;
    const int j0 = (blockIdx.x & 63) * 8;
    const int lane = tid & 63;
    const int wave = tid >> 6;
    const int arow = wave * 16 + (lane & 15);
    const int kOff = (lane >> 4) * 8;
    const int jcol = j0 + (lane & 7);
    const int hrowb = wave * 16 + ((lane >> 4) << 2);
    const bool lo = (lane & 8) == 0;
    uint32_t* const cline = cnt + (dir * 4 + wave) * 32;
    const uint32_t vstore = (uint32_t)(tid + 1);

    for (int s = 0; s < iters; ++s) {
        if (s > 0) {
            const uint32_t target = 64u * (uint32_t)s;
            for (;;) {
                uint32_t v;
                asm volatile(
                    "global_load_dword %0, %1, off sc0 sc1\n\t"
                    "s_waitcnt vmcnt(0)"
                    : "=v"(v) : "v"(cline) : "memory");
                if (__builtin_amdgcn_readfirstlane(v) >= target) break;
                __builtin_amdgcn_s_sleep(1);
            }
            __builtin_amdgcn_sched_barrier(0);
            const unsigned short* hp =
                hbuf + (((dir << 1) | ((s - 1) & 1)) * BATCH + arow) * HH + kOff;
            vshort8 hd[16];
#pragma unroll
            for (int kk = 0; kk < 16; ++kk)
                asm volatile("global_load_dwordx4 %0, %1, off sc0 sc1"
                             : "=v"(hd[kk]) : "v"(hp + kk * 32));
            asm volatile("s_waitcnt vmcnt(0)" ::: "memory");
            __builtin_amdgcn_sched_barrier(0);
#pragma unroll
            for (int kk = 0; kk < 16; ++kk) asm volatile("" :: "v"(hd[kk]));
        }
        unsigned short* hw = hbuf + (size_t)(((dir << 1) | (s & 1)) * BATCH) * HH;
        const int rA = lo ? 0 : 2;
#pragma unroll
        for (int q = 0; q < 2; ++q) {
            int row = hrowb + rA + q;
            unsigned short* wp = hw + row * HH + jcol;
            asm volatile("global_store_short %0, %1, off sc0 sc1"
                         :: "v"(wp), "v"(vstore) : "memory");
        }
        asm volatile("s_waitcnt vmcnt(0)" ::: "memory");
        __builtin_amdgcn_sched_barrier(0);
        if (lane == 0) atomicAdd((unsigned int*)cline, 1u);
    }
}

// ======================= probe: exchange only, fan-in 8 =====================
__launch_bounds__(256, 1)
__global__ void probe_exch8(unsigned short* __restrict__ hbuf,
                            uint32_t* __restrict__ cnt, int iters) {
    __shared__ unsigned short pad[48 * 1024];
    ((volatile unsigned short*)pad)[threadIdx.x] = 0;
    const int tid = threadIdx.x;
    const int dir = blockIdx.x >> 6;
    const int wg = blockIdx.x & 63;
    const int grp = wg >> 3;
    const int j0 = wg * 8;
    const int lane = tid & 63;
    const int wave = tid >> 6;
    const int arow = wave * 16 + (lane & 15);
    const int kOff = (lane >> 4) * 8;
    const int jcol = j0 + (lane & 7);
    const int hrowb = wave * 16 + ((lane >> 4) << 2);
    const bool lo = (lane & 8) == 0;
    uint32_t* const cline = cnt + ((dir * 8 + grp) * 4 + wave) * 32;
    const uint32_t vstore = (uint32_t)(tid + 1);

    for (int s = 0; s < iters; ++s) {
        if (s > 0) {
            const uint32_t target = 8u * (uint32_t)s;
            for (;;) {
                uint32_t v;
                asm volatile(
                    "global_load_dword %0, %1, off sc0 sc1\n\t"
                    "s_waitcnt vmcnt(0)"
                    : "=v"(v) : "v"(cline) : "memory");
                if (__builtin_amdgcn_readfirstlane(v) >= target) break;
                __builtin_amdgcn_s_sleep(1);
            }
            __builtin_amdgcn_sched_barrier(0);
            const unsigned short* hp =
                hbuf + (((dir << 1) | ((s - 1) & 1)) * BATCH + arow) * HH + kOff;
            vshort8 hd[2];
#pragma unroll
            for (int kk = 0; kk < 2; ++kk)
                asm volatile("global_load_dwordx4 %0, %1, off sc0 sc1"
                             : "=v"(hd[kk]) : "v"(hp + kk * 32));
            asm volatile("s_waitcnt vmcnt(0)" ::: "memory");
            __builtin_amdgcn_sched_barrier(0);
#pragma unroll
            for (int kk = 0; kk < 2; ++kk) asm volatile("" :: "v"(hd[kk]));
        }
        unsigned short* hw = hbuf + (size_t)(((dir << 1) | (s & 1)) * BATCH) * HH;
        const int rA = lo ? 0 : 2;
#pragma unroll
        for (int q = 0; q < 2; ++q) {
            int row = hrowb + rA + q;
            unsigned short* wp = hw + row * HH + jcol;
            asm volatile("global_store_short %0, %1, off sc0 sc1"
                         :: "v"(wp), "v"(vstore) : "memory");
        }
        asm volatile("s_waitcnt vmcnt(0)" ::: "memory");
        __builtin_amdgcn_sched_barrier(0);
        if (lane == 0) atomicAdd((unsigned int*)cline, 1u);
    }
}

// ======================= probe: compute only (no sync) ======================
__launch_bounds__(256, 1)
__global__ void probe_comp(const unsigned short* __restrict__ A,
                           const unsigned short* __restrict__ Wi,
                           const float* __restrict__ Whf,
                           const float* __restrict__ bias,
                           unsigned short* __restrict__ hbuf, int iters) {
    __shared__ unsigned short Wlds[NCOLS * 512];  // 32KB (DIN=512)
    __shared__ unsigned short pad[32 * 1024];     // +64KB -> 96KB
    ((volatile unsigned short*)pad)[threadIdx.x] = 0;

    const int tid = threadIdx.x;
    const int dir = blockIdx.x >> 6;
    const int wg = blockIdx.x & 63;
    const int j0 = wg * 8;
    const int lane = tid & 63;
    const int wave = tid >> 6;

    for (int chunk = tid; chunk < NCOLS * 512 / 8; chunk += 256) {
        int n = chunk / 64;
        int k8 = (chunk % 64) * 8;
        int grow = (n >> 3) * HH + j0 + (n & 7);
        vshort8 v = *(const vshort8*)(Wi + ((size_t)dir * 4 * HH + grow) * 512 + k8);
        int byte = n * 1024 + ((k8 * 2) ^ ((n & 7) << 4));
        *(vshort8*)((char*)Wlds + byte) = v;
    }
    __syncthreads();

    const int arow = wave * 16 + (lane & 15);
    const int kOff = (lane >> 4) * 8;
    const int klane = (lane >> 4) * 16;
    const int n0 = lane & 15;
    const int swz = (n0 & 7) << 4;
    const int nb0 = n0 * 1024;
    const int nb1 = (16 + n0) * 1024;
    const int grow0 = (n0 >> 3) * HH + j0 + (n0 & 7);
    const int grow1 = ((n0 >> 3) + 2) * HH + j0 + (n0 & 7);
    const float bias0 = bias[dir * 4 * HH + grow0];
    const float bias1 = bias[dir * 4 * HH + grow1];
    const bool lo = (lane & 8) == 0;
    const int jcol = j0 + (lane & 7);
    const int hrowb = wave * 16 + ((lane >> 4) << 2);

    const float* whf0 = Whf + ((size_t)dir * 4 * HH + grow0) * HH + kOff;
    const float* whf1 = Whf + ((size_t)dir * 4 * HH + grow1) * HH + kOff;
    vshort8 wh0r[16], wh1r[16];
#pragma unroll
    for (int kk = 0; kk < 16; ++kk) {
        float4 a0 = *(const float4*)(whf0 + kk * 32);
        float4 a1 = *(const float4*)(whf0 + kk * 32 + 4);
        float4 b0 = *(const float4*)(whf1 + kk * 32);
        float4 b1 = *(const float4*)(whf1 + kk * 32 + 4);
        vshort8 a, b;
        a[0] = (short)f2bf(a0.x); a[1] = (short)f2bf(a0.y);
        a[2] = (short)f2bf(a0.z); a[3] = (short)f2bf(a0.w);
        a[4] = (short)f2bf(a1.x); a[5] = (short)f2bf(a1.y);
        a[6] = (short)f2bf(a1.z); a[7] = (short)f2bf(a1.w);
        b[0] = (short)f2bf(b0.x); b[1] = (short)f2bf(b0.y);
        b[2] = (short)f2bf(b0.z); b[3] = (short)f2bf(b0.w);
        b[4] = (short)f2bf(b1.x); b[5] = (short)f2bf(b1.y);
        b[6] = (short)f2bf(b1.z); b[7] = (short)f2bf(b1.w);
        wh0r[kk] = a;
        wh1r[kk] = b;
        asm volatile("" : "+v"(wh0r[kk]), "+v"(wh1r[kk]));
    }

    float cstate[4] = {0.f, 0.f, 0.f, 0.f};

    for (int s = 0; s < iters; ++s) {
        const int st = s & (TT - 1);
        const int t = dir ? (TT - 1 - st) : st;

        vfloat4 acc0, acc1;
        acc0[0] = acc0[1] = acc0[2] = acc0[3] = bias0;
        acc1[0] = acc1[1] = acc1[2] = acc1[3] = bias1;

        const unsigned short* ap = A + ((size_t)t * BATCH + arow) * 512 + kOff;
#pragma unroll 8
        for (int kk = 0; kk < 16; ++kk) {
            vshort8 a = *(const vshort8*)(ap + kk * 32);
            int kb = kk * 64 + klane;
            vshort8 b0 = *(const vshort8*)((const char*)Wlds + nb0 + (kb ^ swz));
            vshort8 b1 = *(const vshort8*)((const char*)Wlds + nb1 + (kb ^ swz));
            acc0 = mfma16(a, b0, acc0);
            acc1 = mfma16(a, b1, acc1);
        }

        if (s > 0) {
            // plain cached loads: same bytes as the real h-read, no coherence
            const unsigned short* hp =
                hbuf + (((dir << 1) | ((s - 1) & 1)) * BATCH + arow) * HH + kOff;
            vshort8 hd[16];
#pragma unroll
            for (int kk = 0; kk < 16; ++kk)
                hd[kk] = *(const vshort8*)(hp + kk * 32);
#pragma unroll
            for (int kk = 0; kk < 16; ++kk) {
                acc0 = mfma16(hd[kk], wh0r[kk], acc0);
                acc1 = mfma16(hd[kk], wh1r[kk], acc1);
            }
        }

        float hval[4];
#pragma unroll
        for (int r = 0; r < 4; ++r) {
            float own0 = acc0[r], own1 = acc1[r];
            float oth0 = __shfl_xor(own0, 8, 64);
            float oth1 = __shfl_xor(own1, 8, 64);
            float iv = lo ? own0 : oth0;
            float fv = lo ? oth0 : own0;
            float gv = lo ? own1 : oth1;
            float ov = lo ? oth1 : own1;
            float cnew = sigmoidf_(fv) * cstate[r] + sigmoidf_(iv) * tanhf_(gv);
            cstate[r] = cnew;
            hval[r] = sigmoidf_(ov) * tanhf_(cnew);
        }

        unsigned short* hw = hbuf + (size_t)(((dir << 1) | (s & 1)) * BATCH) * HH;
        const int rA = lo ? 0 : 2;
#pragma unroll
        for (int q = 0; q < 2; ++q) {
            int row = hrowb + rA + q;
            hw[row * HH + jcol] = f2bf(hval[rA + q]);  // plain store
        }
    }
}

extern "C" void kernel_launch(void* const* d_in, const int* in_sizes, int n_in,
                              void* d_out, int out_size, void* d_ws, size_t ws_size,
                              hipStream_t stream) {
    const float* x = (const float*)d_in[0];
    const float* Wi0 = (const float*)d_in[1];
    const float* Wh0 = (const float*)d_in[2];
    const float* b0 = (const float*)d_in[3];
    const float* Wi1 = (const float*)d_in[4];
    const float* Wh1 = (const float*)d_in[5];
    const float* b1 = (const float*)d_in[6];

    char* ws = (char*)d_ws;
    // ws layout (bytes)
    uint32_t* cntA = (uint32_t*)(ws);                          // 1KB
    uint32_t* cntB = (uint32_t*)(ws + 2048);                   // 1KB
    unsigned short* hbufA = (unsigned short*)(ws + 8192);      // 256KB
    unsigned short* hbufB = (unsigned short*)(ws + 270336);    // 256KB
    unsigned short* wi0b = (unsigned short*)(ws + 1048576);    // 4MB
    unsigned short* wi1b = (unsigned short*)(ws + 5242880);    // 8MB
    unsigned short* xb = (unsigned short*)(ws + 13631488);     // 32MB
    unsigned short* o0 = (unsigned short*)(ws + 47185920);     // 64MB -> 114294784
    uint32_t* pcnt64 = (uint32_t*)(ws + 114294784);            // 1KB probe cnts
    uint32_t* pcnt8 = (uint32_t*)(ws + 114298880);             // 8KB probe cnts

    float* out = (float*)d_out;
    const size_t O1SZ = (size_t)TT * BATCH * 2 * HH;
    float* hn_base = out + O1SZ;
    float* cn_base = out + O1SZ + 4 * BATCH * HH;

    // zero phase + probe counters every call (replay-safe)
    hipMemsetAsync(ws, 0, 4096, stream);
    hipMemsetAsync(ws + 114294784, 0, 16384, stream);

    // fp32 -> bf16 conversions
    {
        int n;
        n = TT * BATCH * 512;
        cvt_f32_bf16<<<n / 1024, 256, 0, stream>>>(x, xb, n);
        n = 2 * 2048 * 512;
        cvt_f32_bf16<<<n / 1024, 256, 0, stream>>>(Wi0, wi0b, n);
        n = 2 * 2048 * 1024;
        cvt_f32_bf16<<<n / 1024, 256, 0, stream>>>(Wi1, wi1b, n);
    }

    // phase A: layer 0
    lstm_phase<512, true><<<128, 256, 0, stream>>>(
        xb, wi0b, Wh0, b0, hbufA, cntA, o0, nullptr, hn_base, cn_base);

    // phase B: layer 1
    lstm_phase<1024, false><<<128, 256, 0, stream>>>(
        o0, wi1b, Wh1, b1, hbufB, cntB, nullptr, out,
        hn_base + 2 * BATCH * HH, cn_base + 2 * BATCH * HH);

    // ---- diagnostic probes (scratch only; sized to land in rocprof top-5) ----
    probe_exch64<<<128, 256, 0, stream>>>(hbufA, pcnt64, 3072);
    probe_exch8<<<128, 256, 0, stream>>>(hbufA, pcnt8, 8192);
    probe_comp<<<128, 256, 0, stream>>>(xb, wi0b, Wh0, b0, hbufA, 12288);
}

// Round 12
// 8827.110 us; speedup vs baseline: 13.2872x; 13.2872x over previous
//
#include <hip/hip_runtime.h>
#include <stdint.h>

// 2-layer bidirectional LSTM, T=512 B=64 D=512 H=512.
// Wave-specialized phase kernel: 512 threads = 4 CONSUMER waves (recurrence
// critical path: h exchange + h-GEMM + cell update) + 4 PRODUCER waves
// (x-part gx = bias + x_t@Wi^T computed up to 4 steps ahead into an LDS ring).
// Probe round (R11) showed compute-only = 5.0us/step (sync-free!) at 1 wave/
// SIMD: the x-GEMM's A-loads/LDS/MFMA dominated the serial chain. Producers
// remove them from the critical path; 8 waves/CU gives 2/SIMD latency hiding.
// Global h exchange: R10's proven per-(dir,wave) counter protocol, unchanged.

#define TT 512
#define BATCH 64
#define HH 512
#define NWG 64
#define NCOLS 32

typedef __attribute__((ext_vector_type(8))) short vshort8;
typedef __attribute__((ext_vector_type(4))) float vfloat4;

__device__ __forceinline__ vfloat4 mfma16(vshort8 a, vshort8 b, vfloat4 c) {
    return __builtin_amdgcn_mfma_f32_16x16x32_bf16(a, b, c, 0, 0, 0);
}

__device__ __forceinline__ float sigmoidf_(float x) {
    return 1.f / (1.f + __expf(-x));
}
__device__ __forceinline__ float tanhf_(float x) {
    float e = __expf(2.f * x);
    return 1.f - 2.f / (e + 1.f);
}
__device__ __forceinline__ unsigned short f2bf(float f) {
    uint32_t u = __float_as_uint(f);
    uint32_t r = (u + 0x7fffu + ((u >> 16) & 1u)) >> 16;
    return (unsigned short)r;
}

__global__ void cvt_f32_bf16(const float* __restrict__ src,
                             unsigned short* __restrict__ dst, int n) {
    int i = (blockIdx.x * blockDim.x + threadIdx.x) * 4;
    if (i + 3 < n) {
        float4 v = *(const float4*)(src + i);
        uint2 p;
        p.x = (uint32_t)f2bf(v.x) | ((uint32_t)f2bf(v.y) << 16);
        p.y = (uint32_t)f2bf(v.z) | ((uint32_t)f2bf(v.w) << 16);
        *(uint2*)(dst + i) = p;
    }
}

// DIN: input feature size of this layer (512 or 1024).
// WRITE_BF16: phase A writes bf16 o0; else writes fp32 o1 to d_out.
template <int DIN, bool WRITE_BF16>
__launch_bounds__(512, 1)
__global__ void lstm_phase(const unsigned short* __restrict__ A,   // [T][B][DIN] bf16
                           const unsigned short* __restrict__ Wi,  // [2][4H][DIN] bf16
                           const float* __restrict__ Whf,          // [2][4H][H] f32
                           const float* __restrict__ bias,         // [2][4H] f32
                           unsigned short* __restrict__ hbuf,      // [2][2][B][H] bf16
                           uint32_t* __restrict__ cnt,             // [2][4] x 128B lines
                           unsigned short* __restrict__ obf,       // [T][B][2H] bf16 (A)
                           float* __restrict__ of32,               // [T][B][2H] f32 (B)
                           float* __restrict__ hn,                 // [2][B][H] f32
                           float* __restrict__ cn)                 // [2][B][H] f32
{
    __shared__ unsigned short Wlds[NCOLS * DIN];          // Wi slice (32/64KB)
    __shared__ unsigned short Whlds[NCOLS * HH];          // Wh slice (32KB)
    __shared__ __align__(16) float gxT[4][NCOLS][68];     // gx ring, transposed+padded
    __shared__ int gxflag[4];                             // producer -> consumer
    __shared__ int cflag[4][4];                           // consumer -> producer (WAR)

    const int tid = threadIdx.x;
    const int dir = blockIdx.x >> 6;
    const int wg = blockIdx.x & 63;
    const int j0 = wg * 8;
    const int lane = tid & 63;
    const int wave = tid >> 6;

    if (tid < 4) gxflag[tid] = 0;
    if (tid >= 4 && tid < 20) cflag[(tid - 4) >> 2][(tid - 4) & 3] = 0;

    // ---- stage Wi slice into LDS (swizzled: byte ^= (n&7)<<4) ----
    for (int chunk = tid; chunk < NCOLS * DIN / 8; chunk += 512) {
        int n = chunk / (DIN / 8);
        int k8 = (chunk % (DIN / 8)) * 8;
        int grow = (n >> 3) * HH + j0 + (n & 7);
        vshort8 v = *(const vshort8*)(Wi + ((size_t)dir * 4 * HH + grow) * DIN + k8);
        int byte = n * DIN * 2 + ((k8 * 2) ^ ((n & 7) << 4));
        *(vshort8*)((char*)Wlds + byte) = v;
    }
    // ---- stage Wh slice into LDS with f32->bf16 cvt (same swizzle) ----
    for (int chunk = tid; chunk < NCOLS * HH / 8; chunk += 512) {
        int n = chunk / (HH / 8);
        int k8 = (chunk % (HH / 8)) * 8;
        int grow = (n >> 3) * HH + j0 + (n & 7);
        const float* src = Whf + ((size_t)dir * 4 * HH + grow) * HH + k8;
        float4 f0 = *(const float4*)(src);
        float4 f1 = *(const float4*)(src + 4);
        vshort8 v;
        v[0] = (short)f2bf(f0.x); v[1] = (short)f2bf(f0.y);
        v[2] = (short)f2bf(f0.z); v[3] = (short)f2bf(f0.w);
        v[4] = (short)f2bf(f1.x); v[5] = (short)f2bf(f1.y);
        v[6] = (short)f2bf(f1.z); v[7] = (short)f2bf(f1.w);
        int byte = n * HH * 2 + ((k8 * 2) ^ ((n & 7) << 4));
        *(vshort8*)((char*)Whlds + byte) = v;
    }
    __syncthreads();

    const int kOff = (lane >> 4) * 8;
    const int klane = (lane >> 4) * 16;
    const int n0 = lane & 15;
    const int swz = (n0 & 7) << 4;

    if (wave >= 4) {
        // ========================= PRODUCER wave =========================
        const int p = wave - 4;  // owns ring slot p; steps s = p, p+4, ...
        const int nb0 = n0 * DIN * 2;
        const int nb1 = (16 + n0) * DIN * 2;
        const int grow0 = (n0 >> 3) * HH + j0 + (n0 & 7);
        const int grow1 = ((n0 >> 3) + 2) * HH + j0 + (n0 & 7);
        const float bias0 = bias[dir * 4 * HH + grow0];
        const float bias1 = bias[dir * 4 * HH + grow1];
        float* const g0 = &gxT[p][n0][(lane >> 4) * 4];
        float* const g1 = &gxT[p][16 + n0][(lane >> 4) * 4];

        for (int s = p; s < TT; s += 4) {
            if (s >= 4) {  // WAR gate: consumers done reading step s-4
                for (;;) {
                    int ok = 1;
#pragma unroll
                    for (int c2 = 0; c2 < 4; ++c2)
                        ok &= (__hip_atomic_load(&cflag[p][c2], __ATOMIC_RELAXED,
                                                 __HIP_MEMORY_SCOPE_WORKGROUP) >= s - 3);
                    if (ok) break;
                    __builtin_amdgcn_s_sleep(1);
                }
            }
            const int t = dir ? (TT - 1 - s) : s;
            vfloat4 xa0, xa1, xa2, xa3, xb0, xb1, xb2, xb3;
            xa0[0]=xa0[1]=xa0[2]=xa0[3]=bias0; xa1=xa0; xa2=xa0; xa3=xa0;
            xb0[0]=xb0[1]=xb0[2]=xb0[3]=bias1; xb1=xb0; xb2=xb0; xb3=xb0;

            const unsigned short* ap =
                A + ((size_t)t * BATCH + (lane & 15)) * DIN + kOff;
#pragma unroll 4
            for (int kk = 0; kk < DIN / 32; ++kk) {
                int kb = kk * 64 + klane;
                vshort8 b0 = *(const vshort8*)((const char*)Wlds + nb0 + (kb ^ swz));
                vshort8 b1 = *(const vshort8*)((const char*)Wlds + nb1 + (kb ^ swz));
                vshort8 a0 = *(const vshort8*)(ap + kk * 32);
                vshort8 a1 = *(const vshort8*)(ap + (size_t)16 * DIN + kk * 32);
                vshort8 a2 = *(const vshort8*)(ap + (size_t)32 * DIN + kk * 32);
                vshort8 a3 = *(const vshort8*)(ap + (size_t)48 * DIN + kk * 32);
                xa0 = mfma16(a0, b0, xa0); xb0 = mfma16(a0, b1, xb0);
                xa1 = mfma16(a1, b0, xa1); xb1 = mfma16(a1, b1, xb1);
                xa2 = mfma16(a2, b0, xa2); xb2 = mfma16(a2, b1, xb2);
                xa3 = mfma16(a3, b0, xa3); xb3 = mfma16(a3, b1, xb3);
            }
            *(vfloat4*)(g0)      = xa0; *(vfloat4*)(g1)      = xb0;
            *(vfloat4*)(g0 + 16) = xa1; *(vfloat4*)(g1 + 16) = xb1;
            *(vfloat4*)(g0 + 32) = xa2; *(vfloat4*)(g1 + 32) = xb2;
            *(vfloat4*)(g0 + 48) = xa3; *(vfloat4*)(g1 + 48) = xb3;
            asm volatile("s_waitcnt lgkmcnt(0)" ::: "memory");
            __hip_atomic_store(&gxflag[p], s + 1, __ATOMIC_RELAXED,
                               __HIP_MEMORY_SCOPE_WORKGROUP);
        }
        return;
    }

    // ========================= CONSUMER wave =========================
    const int c = wave;
    const int arow = c * 16 + (lane & 15);
    const int nb0h = n0 * HH * 2;
    const int nb1h = (16 + n0) * HH * 2;
    const bool lo = (lane & 8) == 0;
    const int jcol = j0 + (lane & 7);
    const int hrowb = c * 16 + ((lane >> 4) << 2);
    uint32_t* const cline = cnt + (dir * 4 + c) * 32;
    const float* const gr0 = &gxT[0][n0][c * 16 + (lane >> 4) * 4];
    const float* const gr1 = &gxT[0][16 + n0][c * 16 + (lane >> 4) * 4];
    const int slotStride = NCOLS * 68;

    float cstate[4] = {0.f, 0.f, 0.f, 0.f};

    for (int s = 0; s < TT; ++s) {
        const int t = dir ? (TT - 1 - s) : s;
        const int slot = s & 3;

        // ---- acc init from producer's gx ring slot ----
        while (__hip_atomic_load(&gxflag[slot], __ATOMIC_RELAXED,
                                 __HIP_MEMORY_SCOPE_WORKGROUP) < s + 1)
            __builtin_amdgcn_s_sleep(1);
        vfloat4 acc0 = *(const vfloat4*)(gr0 + slot * slotStride);
        vfloat4 acc1 = *(const vfloat4*)(gr1 + slot * slotStride);
        asm volatile("s_waitcnt lgkmcnt(0)" ::: "memory");
        __builtin_amdgcn_sched_barrier(0);
        if (lane == 0)
            __hip_atomic_store(&cflag[slot][c], s + 1, __ATOMIC_RELAXED,
                               __HIP_MEMORY_SCOPE_WORKGROUP);

        // ---- h exchange (R10 protocol) + h-GEMM from LDS Wh ----
        if (s > 0) {
            const uint32_t target = 64u * (uint32_t)s;
            for (;;) {
                uint32_t v;
                asm volatile(
                    "global_load_dword %0, %1, off sc0 sc1\n\t"
                    "s_waitcnt vmcnt(0)"
                    : "=v"(v) : "v"(cline) : "memory");
                if (__builtin_amdgcn_readfirstlane(v) >= target) break;
                __builtin_amdgcn_s_sleep(1);
            }
            __builtin_amdgcn_sched_barrier(0);

            const unsigned short* hp =
                hbuf + (((dir << 1) | ((s - 1) & 1)) * BATCH + arow) * HH + kOff;
            vshort8 hd[16];
#pragma unroll
            for (int kk = 0; kk < 16; ++kk)
                asm volatile("global_load_dwordx4 %0, %1, off sc0 sc1"
                             : "=v"(hd[kk]) : "v"(hp + kk * 32));
            asm volatile("s_waitcnt vmcnt(0)" ::: "memory");
            __builtin_amdgcn_sched_barrier(0);
#pragma unroll
            for (int kk = 0; kk < 16; ++kk) {
                int kb = kk * 64 + klane;
                vshort8 b0 = *(const vshort8*)((const char*)Whlds + nb0h + (kb ^ swz));
                vshort8 b1 = *(const vshort8*)((const char*)Whlds + nb1h + (kb ^ swz));
                acc0 = mfma16(hd[kk], b0, acc0);
                acc1 = mfma16(hd[kk], b1, acc1);
            }
        }

        // ---- epilogue: exchange i/f and g/o halves, LSTM cell update ----
        float hval[4];
#pragma unroll
        for (int r = 0; r < 4; ++r) {
            float own0 = acc0[r], own1 = acc1[r];
            float oth0 = __shfl_xor(own0, 8, 64);
            float oth1 = __shfl_xor(own1, 8, 64);
            float iv = lo ? own0 : oth0;
            float fv = lo ? oth0 : own0;
            float gv = lo ? own1 : oth1;
            float ov = lo ? oth1 : own1;
            float cnew = sigmoidf_(fv) * cstate[r] + sigmoidf_(iv) * tanhf_(gv);
            cstate[r] = cnew;
            hval[r] = sigmoidf_(ov) * tanhf_(cnew);
        }

        // ---- h stores (sc0 sc1) -> per-wave drain -> counter post ----
        unsigned short* hw = hbuf + (size_t)(((dir << 1) | (s & 1)) * BATCH) * HH;
        const int rA = lo ? 0 : 2;
        unsigned short hb[2];
        hb[0] = f2bf(hval[rA]);
        hb[1] = f2bf(hval[rA + 1]);
#pragma unroll
        for (int q = 0; q < 2; ++q) {
            int row = hrowb + rA + q;
            unsigned short* wp = hw + row * HH + jcol;
            uint32_t v32 = hb[q];
            asm volatile("global_store_short %0, %1, off sc0 sc1"
                         :: "v"(wp), "v"(v32) : "memory");
        }
        asm volatile("s_waitcnt vmcnt(0)" ::: "memory");
        __builtin_amdgcn_sched_barrier(0);
        if (lane == 0) atomicAdd((unsigned int*)cline, 1u);

        // ---- layer output stores (off critical path, after the post) ----
#pragma unroll
        for (int q = 0; q < 2; ++q) {
            int row = hrowb + rA + q;
            if constexpr (WRITE_BF16)
                obf[((size_t)t * BATCH + row) * (2 * HH) + dir * HH + jcol] = hb[q];
            else
                of32[((size_t)t * BATCH + row) * (2 * HH) + dir * HH + jcol] =
                    hval[rA + q];
        }
        if (s == TT - 1) {
#pragma unroll
            for (int q = 0; q < 2; ++q) {
                int r = rA + q, row = hrowb + r;
                hn[(dir * BATCH + row) * HH + jcol] = hval[r];
                cn[(dir * BATCH + row) * HH + jcol] = cstate[r];
            }
        }
    }
}

extern "C" void kernel_launch(void* const* d_in, const int* in_sizes, int n_in,
                              void* d_out, int out_size, void* d_ws, size_t ws_size,
                              hipStream_t stream) {
    const float* x = (const float*)d_in[0];
    const float* Wi0 = (const float*)d_in[1];
    const float* Wh0 = (const float*)d_in[2];
    const float* b0 = (const float*)d_in[3];
    const float* Wi1 = (const float*)d_in[4];
    const float* Wh1 = (const float*)d_in[5];
    const float* b1 = (const float*)d_in[6];

    char* ws = (char*)d_ws;
    // ws layout (bytes); total ~114.3MB (proven footprint)
    uint32_t* cntA = (uint32_t*)(ws);                          // 1KB
    uint32_t* cntB = (uint32_t*)(ws + 2048);                   // 1KB
    unsigned short* hbufA = (unsigned short*)(ws + 8192);      // 256KB
    unsigned short* hbufB = (unsigned short*)(ws + 270336);    // 256KB
    unsigned short* wi0b = (unsigned short*)(ws + 1048576);    // 4MB
    unsigned short* wi1b = (unsigned short*)(ws + 5242880);    // 8MB
    unsigned short* xb = (unsigned short*)(ws + 13631488);     // 32MB
    unsigned short* o0 = (unsigned short*)(ws + 47185920);     // 64MB

    float* out = (float*)d_out;
    const size_t O1SZ = (size_t)TT * BATCH * 2 * HH;
    float* hn_base = out + O1SZ;
    float* cn_base = out + O1SZ + 4 * BATCH * HH;

    // zero both phases' counters every call (replay-safe)
    hipMemsetAsync(ws, 0, 4096, stream);

    // fp32 -> bf16 conversions
    {
        int n;
        n = TT * BATCH * 512;
        cvt_f32_bf16<<<n / 1024, 256, 0, stream>>>(x, xb, n);
        n = 2 * 2048 * 512;
        cvt_f32_bf16<<<n / 1024, 256, 0, stream>>>(Wi0, wi0b, n);
        n = 2 * 2048 * 1024;
        cvt_f32_bf16<<<n / 1024, 256, 0, stream>>>(Wi1, wi1b, n);
    }

    // phase A: layer 0
    lstm_phase<512, true><<<128, 512, 0, stream>>>(
        xb, wi0b, Wh0, b0, hbufA, cntA, o0, nullptr, hn_base, cn_base);

    // phase B: layer 1
    lstm_phase<1024, false><<<128, 512, 0, stream>>>(
        o0, wi1b, Wh1, b1, hbufB, cntB, nullptr, out,
        hn_base + 2 * BATCH * HH, cn_base + 2 * BATCH * HH);
}